// Round 2
// baseline (410.252 us; speedup 1.0000x reference)
//
#include <hip/hip_runtime.h>

// WaterNetModel — R6: fully fused single kernel, one block per site.
//
// R5 post-mortem: 5-kernel pipeline summed to 359 us while total traffic
// (~330 MB) supports ~53 us at the 6.2 TB/s the harness fills demonstrate.
// Cost was structural: 5 launches, per-XCD L2 (4 MB) too small for the
// 18 MB P/T working set (every scan pass ran at L3 latency), 16-way
// redundant same-address loads, and 3 global round-trips of boundary state.
//
// R6: block = 512 threads = 32 chunks x 16 hidden units, one site per
// block (grid = NS = 2048, ~4 blocks/CU). Stage the site's P,T column
// into LDS once (8.8 KB float2), then:
//   phase 1: per-chunk snow summary (A,B)          [LDS reads only]
//   resolveS (16 threads, in LDS): s0 per chunk
//   phase 2: exact s trajectory -> write S (143MB) + h chunk-partial hp
//   resolveH (16 threads, in LDS): h0 per chunk
//   phase 3: recompute s,h -> write H (143MB) + Q (9MB, shfl-reduce)
// Chunk-boundary state lives entirely in 6 KB of LDS; every input byte
// is read from HBM exactly once; stores are the only big traffic.
//
// Recurrences per (site, hh):
//   snow:   s' = max(s + a, b), a = p_neg - melt_pot, b = p_neg
//           composition (A,B)∘(a,b) = (A+a, max(B+a,b))  (associative)
//   linear: h' = cl*(h + xin), cl = 1-gl  -> chunk: h_out = cl^L h_in + hp

constexpr int NT  = 1096;
constexpr int NS  = 2048;
constexpr int NH  = 16;
constexpr int NSH = NS * NH;               // 32768
constexpr int NC  = 32;                    // chunks per site
constexpr int LCH = (NT + NC - 1) / NC;    // 35 (chunks 0..30 len 35, 31 len 11)
constexpr int BT  = NC * NH;               // 512 threads

__device__ __forceinline__ float sigm(float x) { return 1.0f / (1.0f + expf(-x)); }

__global__ __launch_bounds__(BT) void waternet_fused(
    const float* __restrict__ P, const float* __restrict__ T,
    const float* __restrict__ w_i, const float* __restrict__ w_o,
    const float* __restrict__ w_l, const float* __restrict__ w_s,
    float* __restrict__ Q, float* __restrict__ H, float* __restrict__ S)
{
    __shared__ float2 PT[NT];      // this site's (P,T) column: 8.8 KB
    __shared__ float bufA[BT];     // A, then hp
    __shared__ float bufB[BT];     // B, then h0
    __shared__ float bufC[BT];     // s0

    const int tid  = (int)threadIdx.x;
    const int hh   = tid & (NH - 1);
    const int c    = tid >> 4;                 // chunk id 0..31
    const int site = (int)blockIdx.x;

    // ---- cooperative stage of this site's P,T columns (HBM read: once) ----
    for (int t = tid; t < NT; t += BT) {
        const float p  = P[(size_t)t * NS + site];
        const float tt = T[(size_t)t * NS + site];
        PT[t] = make_float2(p, tt);
    }

    const float mc = expf(w_s[hh]) + 1.0f;
    const float gi = sigm(w_i[hh]);
    const float gl = sigm(w_l[hh]);
    const float cl = 1.0f - gl;

    const int t0  = c * LCH;
    const int len = min(NT - t0, LCH);         // 35, last chunk 11

    __syncthreads();

    // ---- phase 1: snow chunk summary (A,B) ----
    float A = 0.0f, B = -1e38f;
    for (int i = 0; i < len; ++i) {
        const float2 pt = PT[t0 + i];
        const float tpos = fmaxf(pt.y, 0.0f);
        const float pnn  = (pt.y < 0.0f) ? pt.x : 0.0f;
        const float at   = pnn - tpos * mc;
        A += at;
        B = fmaxf(B + at, pnn);
    }
    bufA[tid] = A;
    bufB[tid] = B;
    __syncthreads();

    // ---- resolveS: s0 per chunk (16 threads, 32-step serial, trivial) ----
    if (tid < NH) {
        float s = 0.0f;
        for (int k = 0; k < NC; ++k) {
            bufC[k * NH + tid] = s;
            s = fmaxf(s + bufA[k * NH + tid], bufB[k * NH + tid]);
        }
    }
    __syncthreads();

    // ---- phase 2: exact s trajectory (write S) + h chunk-partial hp ----
    float s = bufC[tid];
    float hp = 0.0f;
    {
        float* Sp = S + (size_t)t0 * NSH + (size_t)site * NH + hh;
        for (int i = 0; i < len; ++i) {
            const float2 pt = PT[t0 + i];
            const float tpos = fmaxf(pt.y, 0.0f);
            const float pnn  = (pt.y < 0.0f) ? pt.x : 0.0f;
            const float ppp  = (pt.y > 0.0f) ? pt.x : 0.0f;
            const float m    = fminf(tpos * mc, s);
            s = s - m + pnn;
            Sp[(size_t)i * NSH] = s;                    // 64B/16-lane group
            const float xin = (ppp + m) * gi;
            hp = cl * (hp + xin);
        }
    }
    bufA[tid] = hp;        // bufA's phase-1 contents already consumed
    __syncthreads();

    // ---- resolveH: h0 per chunk ----
    if (tid < NH) {
        const float clr = 1.0f - sigm(w_l[tid]);
        float h = 0.0f;
        for (int k = 0; k < NC; ++k) {
            bufB[k * NH + tid] = h;
            const int lk = min(NT - k * LCH, LCH);
            h = powf(clr, (float)lk) * h + bufA[k * NH + tid];
        }
    }
    __syncthreads();

    // ---- softmax output weights (per-lane, trivial) ----
    float mx = -1e30f;
    #pragma unroll
    for (int j = 0; j < NH; ++j) mx = fmaxf(mx, w_o[j]);
    float den = 0.0f;
    #pragma unroll
    for (int j = 0; j < NH; ++j) den += expf(w_o[j] - mx);
    const float aw = expf(w_o[hh] - mx) / den;

    // ---- phase 3: recompute s,h; write H and Q ----
    s = bufC[tid];
    float h = bufB[tid];
    {
        float* Hp = H + (size_t)t0 * NSH + (size_t)site * NH + hh;
        float* Qp = Q + (size_t)t0 * NS + site;
        for (int i = 0; i < len; ++i) {
            const float2 pt = PT[t0 + i];
            const float tpos = fmaxf(pt.y, 0.0f);
            const float pnn  = (pt.y < 0.0f) ? pt.x : 0.0f;
            const float ppp  = (pt.y > 0.0f) ? pt.x : 0.0f;
            const float m    = fminf(tpos * mc, s);
            s = s - m + pnn;
            const float xin = (ppp + m) * gi;
            const float q   = (xin + h) * gl;
            h = cl * (h + xin);
            Hp[(size_t)i * NSH] = h;
            float qa = q * aw;
            qa += __shfl_xor(qa, 1, 16);
            qa += __shfl_xor(qa, 2, 16);
            qa += __shfl_xor(qa, 4, 16);
            qa += __shfl_xor(qa, 8, 16);
            if (hh == 0) Qp[(size_t)i * NS] = qa;
        }
    }
}

extern "C" void kernel_launch(void* const* d_in, const int* in_sizes, int n_in,
                              void* d_out, int out_size, void* d_ws, size_t ws_size,
                              hipStream_t stream) {
    const float* P   = (const float*)d_in[0];
    const float* T   = (const float*)d_in[1];
    const float* w_i = (const float*)d_in[2];
    const float* w_o = (const float*)d_in[3];
    const float* w_l = (const float*)d_in[4];
    const float* w_s = (const float*)d_in[5];

    float* Q = (float*)d_out;
    float* H = Q + (size_t)NT * NS;
    float* S = H + (size_t)NT * NS * NH;

    // No workspace needed: all intermediate state lives in LDS.
    waternet_fused<<<NS, BT, 0, stream>>>(P, T, w_i, w_o, w_l, w_s, Q, H, S);
}

// Round 3
// 328.715 us; speedup vs baseline: 1.2481x; 1.2481x over previous
//
#include <hip/hip_runtime.h>

// WaterNetModel — R7: fused single kernel, block = 4 sites x 8 chunks x 16 hh.
//
// R6 post-mortem (410 us, regression): one-site-per-block made every S/H
// store a 64 B partial-line RMW (other half of each 128 B line owned by a
// different block/XCD) and made P/T staging fully uncoalesced (stride-8KB
// per lane). R7 keeps the single-kernel fusion but restores R5's store
// geometry: a wave = fixed chunk, 4 consecutive sites x 16 hh = 256 B
// contiguous aligned stores (full lines). Staging reads 16 B-contiguous
// segments; XCD-chunked block swizzle keeps line reuse on-XCD (2.2 MB
// P/T per XCD fits the 4 MB L2). NT = 8*137 exactly -> uniform chunks.
//
// Phases (all in-LDS between barriers):
//   stage P,T column group -> LDS (35 KB, padded: conflict-free)
//   1: per-chunk snow summary (A,B)
//   resolveS (64 threads): s0 per chunk
//   2: exact s trajectory -> store S + h chunk-partial hp
//   resolveH (64 threads): h0 per chunk  (cl^137, uniform)
//   3: recompute s,h -> store H, Q (shfl-reduce over 16 hh lanes)
//
// Recurrences per (site, hh):
//   snow:   s' = max(s + a, b), a = p_neg - melt_pot, b = p_neg
//           composition (A,B)∘(a,b) = (A+a, max(B+a,b))  (associative)
//   linear: h' = cl*(h + xin), cl = 1-gl  -> chunk: h_out = cl^L h_in + hp

constexpr int NT  = 1096;
constexpr int NS  = 2048;
constexpr int NH  = 16;
constexpr int NSH = NS * NH;          // 32768
constexpr int SG  = 4;                // sites per block
constexpr int NC  = 8;                // chunks per site
constexpr int L   = NT / NC;          // 137 exact
static_assert(NC * L == NT, "");
constexpr int BT  = NC * SG * NH;     // 512 threads
constexpr int NXCD = 8;

__device__ __forceinline__ float sigm(float x) { return 1.0f / (1.0f + expf(-x)); }

__global__ __launch_bounds__(BT, 4) void waternet_fused(
    const float* __restrict__ P, const float* __restrict__ T,
    const float* __restrict__ w_i, const float* __restrict__ w_o,
    const float* __restrict__ w_l, const float* __restrict__ w_s,
    float* __restrict__ Q, float* __restrict__ H, float* __restrict__ S)
{
    __shared__ float2 PTs[SG][NT + 2];   // +2 float2 pad: sl lanes hit distinct banks
    __shared__ float bufA[BT];           // A, then hp
    __shared__ float bufB[BT];           // B, then h0
    __shared__ float bufC[BT];           // s0

    // XCD-chunked swizzle: grid 512 = 64 blocks per XCD, contiguous sites per XCD.
    const int nwg = NS / SG;                       // 512
    const int cpx = nwg / NXCD;                    // 64
    const int bid = (int)blockIdx.x;
    const int lbid = (bid % NXCD) * cpx + bid / NXCD;

    const int tid  = (int)threadIdx.x;
    const int hh   = tid & (NH - 1);
    const int sl   = (tid >> 4) & (SG - 1);
    const int c    = tid >> 6;                     // chunk 0..7
    const int site0 = lbid * SG;

    // ---- stage P,T columns for 4 sites (16 B-contiguous per 4 lanes) ----
    for (int e = tid; e < SG * NT; e += BT) {
        const int t  = e >> 2;
        const int s2 = e & 3;
        const float p  = P[(size_t)t * NS + site0 + s2];
        const float tt = T[(size_t)t * NS + site0 + s2];
        PTs[s2][t] = make_float2(p, tt);
    }

    const float mc = expf(w_s[hh]) + 1.0f;
    const float gi = sigm(w_i[hh]);
    const float gl = sigm(w_l[hh]);
    const float cl = 1.0f - gl;

    const int t0 = c * L;
    __syncthreads();

    // ---- phase 1: snow chunk summary (A,B) ----
    float A = 0.0f, B = -1e38f;
    for (int i = 0; i < L; ++i) {
        const float2 pt = PTs[sl][t0 + i];
        const float tpos = fmaxf(pt.y, 0.0f);
        const float pnn  = (pt.y < 0.0f) ? pt.x : 0.0f;
        const float at   = pnn - tpos * mc;
        A += at;
        B = fmaxf(B + at, pnn);
    }
    bufA[tid] = A;
    bufB[tid] = B;
    __syncthreads();

    // ---- resolveS: s0 per chunk (64 threads = 4 sl x 16 hh, 8-step serial) ----
    if (tid < SG * NH) {
        float s = 0.0f;
        #pragma unroll
        for (int k = 0; k < NC; ++k) {
            const int idx = k * (SG * NH) + tid;
            bufC[idx] = s;
            s = fmaxf(s + bufA[idx], bufB[idx]);
        }
    }
    __syncthreads();

    // ---- phase 2: exact s trajectory (store S) + h chunk-partial hp ----
    float s = bufC[tid];
    float hp = 0.0f;
    {
        float* Sp = S + (size_t)t0 * NSH + (size_t)site0 * NH + sl * NH + hh;
        for (int i = 0; i < L; ++i) {
            const float2 pt = PTs[sl][t0 + i];
            const float tpos = fmaxf(pt.y, 0.0f);
            const float pnn  = (pt.y < 0.0f) ? pt.x : 0.0f;
            const float ppp  = (pt.y > 0.0f) ? pt.x : 0.0f;
            const float m    = fminf(tpos * mc, s);
            s = s - m + pnn;
            Sp[(size_t)i * NSH] = s;               // wave: 256 B contiguous
            const float xin = (ppp + m) * gi;
            hp = cl * (hp + xin);
        }
    }
    bufA[tid] = hp;
    __syncthreads();

    // ---- resolveH: h0 per chunk (uniform cl^L) ----
    if (tid < SG * NH) {
        const float clr = 1.0f - sigm(w_l[tid & (NH - 1)]);
        const float clL = powf(clr, (float)L);
        float h = 0.0f;
        #pragma unroll
        for (int k = 0; k < NC; ++k) {
            const int idx = k * (SG * NH) + tid;
            bufB[idx] = h;
            h = clL * h + bufA[idx];
        }
    }
    __syncthreads();

    // ---- softmax output weights ----
    float mx = -1e30f;
    #pragma unroll
    for (int j = 0; j < NH; ++j) mx = fmaxf(mx, w_o[j]);
    float den = 0.0f;
    #pragma unroll
    for (int j = 0; j < NH; ++j) den += expf(w_o[j] - mx);
    const float aw = expf(w_o[hh] - mx) / den;

    // ---- phase 3: recompute s,h; store H and Q ----
    s = bufC[tid];
    float h = bufB[tid];
    {
        float* Hp = H + (size_t)t0 * NSH + (size_t)site0 * NH + sl * NH + hh;
        float* Qp = Q + (size_t)t0 * NS + site0 + sl;
        for (int i = 0; i < L; ++i) {
            const float2 pt = PTs[sl][t0 + i];
            const float tpos = fmaxf(pt.y, 0.0f);
            const float pnn  = (pt.y < 0.0f) ? pt.x : 0.0f;
            const float ppp  = (pt.y > 0.0f) ? pt.x : 0.0f;
            const float m    = fminf(tpos * mc, s);
            s = s - m + pnn;
            const float xin = (ppp + m) * gi;
            const float q   = (xin + h) * gl;
            h = cl * (h + xin);
            Hp[(size_t)i * NSH] = h;               // wave: 256 B contiguous
            float qa = q * aw;
            qa += __shfl_xor(qa, 1, 16);
            qa += __shfl_xor(qa, 2, 16);
            qa += __shfl_xor(qa, 4, 16);
            qa += __shfl_xor(qa, 8, 16);
            if (hh == 0) Qp[(size_t)i * NS] = qa;  // wave: 16 B contiguous
        }
    }
}

extern "C" void kernel_launch(void* const* d_in, const int* in_sizes, int n_in,
                              void* d_out, int out_size, void* d_ws, size_t ws_size,
                              hipStream_t stream) {
    const float* P   = (const float*)d_in[0];
    const float* T   = (const float*)d_in[1];
    const float* w_i = (const float*)d_in[2];
    const float* w_o = (const float*)d_in[3];
    const float* w_l = (const float*)d_in[4];
    const float* w_s = (const float*)d_in[5];

    float* Q = (float*)d_out;
    float* H = Q + (size_t)NT * NS;
    float* S = H + (size_t)NT * NS * NH;

    // No workspace needed: all intermediate state lives in LDS.
    waternet_fused<<<NS / SG, BT, 0, stream>>>(P, T, w_i, w_o, w_l, w_s, Q, H, S);
}

// Round 4
// 316.572 us; speedup vs baseline: 1.2959x; 1.0384x over previous
//
#include <hip/hip_runtime.h>

// WaterNetModel — R8: fused kernel, hh-paired threads, 16 chunks, unroll-4.
//
// R7 post-mortem: dur_us = ~188 us harness fill + ~141 us kernel (additive
// model fits R4-R7). Traffic floor is ~51 us; the ~90 us excess is
// per-iteration cost of the 137-step serial loops: dependent ds_read_b64
// (~120 cyc) each iter with no unrolling, 4 B/lane stores (fill uses 16 B),
// and a ~25 us store-free prologue (stage+phase1) in lockstep.
//
// R8: thread = (chunk, site, hh-PAIR) -> float2 stores (half the store
// instrs), one LDS read per 2 hidden units, 3-step Q shfl. NC 8->16
// (chunks 69/68; wave never straddles the boundary -> uniform len per
// wave). Inner loops unrolled x4 (batched LDS reads). float4 staging.
// Keeps R7's full-line store geometry + XCD swizzle + in-LDS resolves.
//
// Recurrences per (site, hh):
//   snow:   s' = max(s + a, b), a = p_neg - melt_pot, b = p_neg
//           composition (A,B)∘(a,b) = (A+a, max(B+a,b))  (associative)
//   linear: h' = cl*(h + xin), cl = 1-gl -> chunk: h_out = cl^len h_in + hp

constexpr int NT  = 1096;
constexpr int NS  = 2048;
constexpr int NH  = 16;
constexpr int NSH = NS * NH;          // 32768
constexpr int SG  = 4;                // sites per block
constexpr int NC  = 16;               // chunks per site: 8 of len 69, 8 of len 68
constexpr int LA  = 69;
constexpr int LB  = 68;               // 8*69 + 8*68 = 1096
constexpr int BT  = 512;              // NC(16) x SG(4) x hh2(8)
constexpr int NXCD = 8;

__device__ __forceinline__ float sigm(float x) { return 1.0f / (1.0f + expf(-x)); }

__global__ __launch_bounds__(BT, 4) void waternet_fused(
    const float* __restrict__ P, const float* __restrict__ T,
    const float* __restrict__ w_i, const float* __restrict__ w_o,
    const float* __restrict__ w_l, const float* __restrict__ w_s,
    float* __restrict__ Q, float* __restrict__ H, float* __restrict__ S)
{
    __shared__ float2 PTs[SG][NT + 2];     // 35.1 KB, sl-stride hits distinct banks
    __shared__ float bufA[BT * 2];         // A / hp   (per c,sl,hh2,parity)
    __shared__ float bufB[BT * 2];         // B / h0
    __shared__ float bufC[BT * 2];         // s0

    // XCD-chunked bijective swizzle (512 blocks = 64 per XCD, contiguous sites)
    const int nwg  = NS / SG;                      // 512
    const int cpx  = nwg / NXCD;                   // 64
    const int bid  = (int)blockIdx.x;
    const int lbid = (bid % NXCD) * cpx + bid / NXCD;

    const int tid  = (int)threadIdx.x;
    const int hh2  = tid & 7;                      // hidden pair: hh = 2*hh2+p
    const int sl   = (tid >> 3) & (SG - 1);
    const int c    = tid >> 5;                     // chunk 0..15
    const int site0 = lbid * SG;

    // chunk geometry: c<8 -> t0=69c len 69 ; c>=8 -> t0=552+68(c-8) len 68
    const int t0  = (c < 8) ? (LA * c) : (LA * 8 + LB * (c - 8));
    const int len = (c < 8) ? LA : LB;             // uniform within each wave

    // ---- stage P,T for 4 sites via float4 row-segments ----
    for (int t = tid; t < NT; t += BT) {
        const float4 p4 = *(const float4*)(P + (size_t)t * NS + site0);
        const float4 t4 = *(const float4*)(T + (size_t)t * NS + site0);
        PTs[0][t] = make_float2(p4.x, t4.x);
        PTs[1][t] = make_float2(p4.y, t4.y);
        PTs[2][t] = make_float2(p4.z, t4.z);
        PTs[3][t] = make_float2(p4.w, t4.w);
    }

    float mc[2], gi[2], gl[2], cl[2];
    #pragma unroll
    for (int p = 0; p < 2; ++p) {
        const int hh = hh2 * 2 + p;
        mc[p] = expf(w_s[hh]) + 1.0f;
        gi[p] = sigm(w_i[hh]);
        gl[p] = sigm(w_l[hh]);
        cl[p] = 1.0f - gl[p];
    }

    __syncthreads();

    // ---- phase 1: snow chunk summary (A,B), unroll x4 ----
    float A[2] = {0.0f, 0.0f}, B[2] = {-1e38f, -1e38f};
    {
        const float2* pts = &PTs[sl][t0];
        auto stepAB = [&](float2 pt) {
            const float tpos = fmaxf(pt.y, 0.0f);
            const float pnn  = (pt.y < 0.0f) ? pt.x : 0.0f;
            #pragma unroll
            for (int p = 0; p < 2; ++p) {
                const float at = pnn - tpos * mc[p];
                A[p] += at;
                B[p] = fmaxf(B[p] + at, pnn);
            }
        };
        int i = 0;
        for (; i + 4 <= len; i += 4) {
            float2 v0 = pts[i], v1 = pts[i+1], v2 = pts[i+2], v3 = pts[i+3];
            stepAB(v0); stepAB(v1); stepAB(v2); stepAB(v3);
        }
        for (; i < len; ++i) stepAB(pts[i]);
    }
    bufA[tid * 2]     = A[0];
    bufA[tid * 2 + 1] = A[1];
    bufB[tid * 2]     = B[0];
    bufB[tid * 2 + 1] = B[1];
    __syncthreads();

    // ---- resolveS: 64 threads (sl x hh), 16-step serial in LDS ----
    if (tid < SG * NH) {
        const int rsl = tid >> 4, rhh = tid & 15;
        const int sub = rsl * 16 + rhh;            // (sl*8+hh2)*2+p
        float s = 0.0f;
        #pragma unroll
        for (int k = 0; k < NC; ++k) {
            const int idx = k * 64 + sub;
            bufC[idx] = s;
            s = fmaxf(s + bufA[idx], bufB[idx]);
        }
    }
    __syncthreads();

    // ---- phase 2: exact s trajectory (store S as float2) + h partial hp ----
    float s[2], hp[2] = {0.0f, 0.0f};
    s[0] = bufC[tid * 2];
    s[1] = bufC[tid * 2 + 1];
    {
        const float2* pts = &PTs[sl][t0];
        float2* Sp = (float2*)(S + (size_t)t0 * NSH + (size_t)site0 * NH
                               + sl * NH + hh2 * 2);
        auto step2 = [&](float2 pt, int i) {
            const float tpos = fmaxf(pt.y, 0.0f);
            const float pnn  = (pt.y < 0.0f) ? pt.x : 0.0f;
            const float ppp  = (pt.y > 0.0f) ? pt.x : 0.0f;
            float2 sv;
            #pragma unroll
            for (int p = 0; p < 2; ++p) {
                const float m = fminf(tpos * mc[p], s[p]);
                s[p] = s[p] - m + pnn;
                const float xin = (ppp + m) * gi[p];
                hp[p] = cl[p] * (hp[p] + xin);
                (p ? sv.y : sv.x) = s[p];
            }
            Sp[(size_t)i * (NSH / 2)] = sv;        // half-wave: 256 B contiguous
        };
        int i = 0;
        for (; i + 4 <= len; i += 4) {
            float2 v0 = pts[i], v1 = pts[i+1], v2 = pts[i+2], v3 = pts[i+3];
            step2(v0, i); step2(v1, i+1); step2(v2, i+2); step2(v3, i+3);
        }
        for (; i < len; ++i) step2(pts[i], i);
    }
    bufA[tid * 2]     = hp[0];
    bufA[tid * 2 + 1] = hp[1];
    __syncthreads();

    // ---- resolveH: 64 threads, h0 per chunk ----
    if (tid < SG * NH) {
        const int rsl = tid >> 4, rhh = tid & 15;
        const int sub = rsl * 16 + rhh;
        const float clr = 1.0f - sigm(w_l[rhh]);
        const float pA = powf(clr, (float)LA);
        const float pB = powf(clr, (float)LB);
        float h = 0.0f;
        #pragma unroll
        for (int k = 0; k < NC; ++k) {
            const int idx = k * 64 + sub;
            bufB[idx] = h;
            h = ((k < 8) ? pA : pB) * h + bufA[idx];
        }
    }
    __syncthreads();

    // ---- softmax output weights ----
    float aw[2];
    {
        float mx = -1e30f;
        #pragma unroll
        for (int j = 0; j < NH; ++j) mx = fmaxf(mx, w_o[j]);
        float den = 0.0f;
        #pragma unroll
        for (int j = 0; j < NH; ++j) den += expf(w_o[j] - mx);
        aw[0] = expf(w_o[hh2 * 2]     - mx) / den;
        aw[1] = expf(w_o[hh2 * 2 + 1] - mx) / den;
    }

    // ---- phase 3: recompute s,h; store H (float2) and Q (shfl over 8) ----
    s[0] = bufC[tid * 2];
    s[1] = bufC[tid * 2 + 1];
    float h[2];
    h[0] = bufB[tid * 2];
    h[1] = bufB[tid * 2 + 1];
    {
        const float2* pts = &PTs[sl][t0];
        float2* Hp = (float2*)(H + (size_t)t0 * NSH + (size_t)site0 * NH
                               + sl * NH + hh2 * 2);
        float* Qp = Q + (size_t)t0 * NS + site0 + sl;
        auto step3 = [&](float2 pt, int i) {
            const float tpos = fmaxf(pt.y, 0.0f);
            const float pnn  = (pt.y < 0.0f) ? pt.x : 0.0f;
            const float ppp  = (pt.y > 0.0f) ? pt.x : 0.0f;
            float2 hv;
            float qa = 0.0f;
            #pragma unroll
            for (int p = 0; p < 2; ++p) {
                const float m = fminf(tpos * mc[p], s[p]);
                s[p] = s[p] - m + pnn;
                const float xin = (ppp + m) * gi[p];
                const float q   = (xin + h[p]) * gl[p];
                h[p] = cl[p] * (h[p] + xin);
                (p ? hv.y : hv.x) = h[p];
                qa += q * aw[p];
            }
            Hp[(size_t)i * (NSH / 2)] = hv;
            qa += __shfl_xor(qa, 1, 8);
            qa += __shfl_xor(qa, 2, 8);
            qa += __shfl_xor(qa, 4, 8);
            if (hh2 == 0) Qp[(size_t)i * NS] = qa;
        };
        int i = 0;
        for (; i + 4 <= len; i += 4) {
            float2 v0 = pts[i], v1 = pts[i+1], v2 = pts[i+2], v3 = pts[i+3];
            step3(v0, i); step3(v1, i+1); step3(v2, i+2); step3(v3, i+3);
        }
        for (; i < len; ++i) step3(pts[i], i);
    }
}

extern "C" void kernel_launch(void* const* d_in, const int* in_sizes, int n_in,
                              void* d_out, int out_size, void* d_ws, size_t ws_size,
                              hipStream_t stream) {
    const float* P   = (const float*)d_in[0];
    const float* T   = (const float*)d_in[1];
    const float* w_i = (const float*)d_in[2];
    const float* w_o = (const float*)d_in[3];
    const float* w_l = (const float*)d_in[4];
    const float* w_s = (const float*)d_in[5];

    float* Q = (float*)d_out;
    float* H = Q + (size_t)NT * NS;
    float* S = H + (size_t)NT * NS * NH;

    // No workspace needed: all intermediate state lives in LDS.
    waternet_fused<<<NS / SG, BT, 0, stream>>>(P, T, w_i, w_o, w_l, w_s, Q, H, S);
}

// Round 5
// 315.260 us; speedup vs baseline: 1.3013x; 1.0042x over previous
//
#include <hip/hip_runtime.h>

// WaterNetModel — R9: fused kernel, 8 sites/block -> 512 B store granules.
//
// R8 post-mortem: kernel ~129 us for ~315 MB = 2.4 TB/s while the harness
// fill hits 6.3 TB/s. Issue/latency arithmetic rules out compute (~6 us
// issue, ~3 us chains). Theory: SG=4 makes every store a 256 B granule at
// 128 KB plane stride; scattered 256 B HBM bursts cost ~2.5x in row
// activations vs the fill's sequential 1 KB stream.
//
// R9: SG=8 (max that still covers 256 CUs: grid = NS/8 = 256), BT=1024 =
// 16 chunks x 8 sites x 8 hh-pairs. A wave = exactly one chunk: 8 sl x
// 8 hh2 x float2 = 512 B contiguous aligned per store instruction (2x R8).
// 1 block/CU, 16 waves, LDS 94 KB (70 KB PT stage + 24 KB resolve bufs).
// Everything else (phases, in-LDS resolves, XCD swizzle, unroll-4) as R8.
//
// Recurrences per (site, hh):
//   snow:   s' = max(s + a, b), a = p_neg - melt_pot, b = p_neg
//           composition (A,B)∘(a,b) = (A+a, max(B+a,b))  (associative)
//   linear: h' = cl*(h + xin), cl = 1-gl -> chunk: h_out = cl^len h_in + hp

constexpr int NT  = 1096;
constexpr int NS  = 2048;
constexpr int NH  = 16;
constexpr int NSH = NS * NH;          // 32768
constexpr int SG  = 8;                // sites per block
constexpr int NC  = 16;               // chunks per site: 8 of len 69, 8 of len 68
constexpr int LA  = 69;
constexpr int LB  = 68;               // 8*69 + 8*68 = 1096
constexpr int BT  = 1024;             // NC(16) x SG(8) x hh2(8)
constexpr int NXCD = 8;
constexpr int RES = SG * NH;          // 128 resolve threads / states per chunk

__device__ __forceinline__ float sigm(float x) { return 1.0f / (1.0f + expf(-x)); }

__global__ __launch_bounds__(BT, 1) void waternet_fused(
    const float* __restrict__ P, const float* __restrict__ T,
    const float* __restrict__ w_i, const float* __restrict__ w_o,
    const float* __restrict__ w_l, const float* __restrict__ w_s,
    float* __restrict__ Q, float* __restrict__ H, float* __restrict__ S)
{
    __shared__ float2 PTs[SG][NT + 2];     // 70.3 KB; sl-stride -> distinct banks
    __shared__ float bufA[BT * 2];         // A / hp   (idx = c*128 + sl*16 + hh)
    __shared__ float bufB[BT * 2];         // B / h0
    __shared__ float bufC[BT * 2];         // s0

    // XCD-chunked bijective swizzle: 256 blocks = 32 per XCD, contiguous sites.
    const int nwg  = NS / SG;                      // 256
    const int cpx  = nwg / NXCD;                   // 32
    const int bid  = (int)blockIdx.x;
    const int lbid = (bid % NXCD) * cpx + bid / NXCD;

    const int tid  = (int)threadIdx.x;
    const int hh2  = tid & 7;                      // hidden pair: hh = 2*hh2+p
    const int sl   = (tid >> 3) & (SG - 1);
    const int c    = tid >> 6;                     // chunk 0..15 (uniform per wave)
    const int site0 = lbid * SG;

    // chunk geometry: c<8 -> t0=69c len 69 ; c>=8 -> t0=552+68(c-8) len 68
    const int t0  = (c < 8) ? (LA * c) : (LA * 8 + LB * (c - 8));
    const int len = (c < 8) ? LA : LB;

    // ---- stage P,T for 8 sites (32 B row segments per 8 lanes) ----
    for (int e = tid; e < SG * NT; e += BT) {
        const int t  = e >> 3;
        const int s2 = e & 7;
        const float p  = P[(size_t)t * NS + site0 + s2];
        const float tt = T[(size_t)t * NS + site0 + s2];
        PTs[s2][t] = make_float2(p, tt);
    }

    float mc[2], gi[2], gl[2], cl[2];
    #pragma unroll
    for (int p = 0; p < 2; ++p) {
        const int hh = hh2 * 2 + p;
        mc[p] = expf(w_s[hh]) + 1.0f;
        gi[p] = sigm(w_i[hh]);
        gl[p] = sigm(w_l[hh]);
        cl[p] = 1.0f - gl[p];
    }

    __syncthreads();

    // ---- phase 1: snow chunk summary (A,B), unroll x4 ----
    float A[2] = {0.0f, 0.0f}, B[2] = {-1e38f, -1e38f};
    {
        const float2* pts = &PTs[sl][t0];
        auto stepAB = [&](float2 pt) {
            const float tpos = fmaxf(pt.y, 0.0f);
            const float pnn  = (pt.y < 0.0f) ? pt.x : 0.0f;
            #pragma unroll
            for (int p = 0; p < 2; ++p) {
                const float at = pnn - tpos * mc[p];
                A[p] += at;
                B[p] = fmaxf(B[p] + at, pnn);
            }
        };
        int i = 0;
        for (; i + 4 <= len; i += 4) {
            float2 v0 = pts[i], v1 = pts[i+1], v2 = pts[i+2], v3 = pts[i+3];
            stepAB(v0); stepAB(v1); stepAB(v2); stepAB(v3);
        }
        for (; i < len; ++i) stepAB(pts[i]);
    }
    bufA[tid * 2]     = A[0];
    bufA[tid * 2 + 1] = A[1];
    bufB[tid * 2]     = B[0];
    bufB[tid * 2 + 1] = B[1];
    __syncthreads();

    // ---- resolveS: 128 threads (sl x hh), 16-step serial in LDS ----
    if (tid < RES) {
        float s = 0.0f;
        #pragma unroll
        for (int k = 0; k < NC; ++k) {
            const int idx = k * RES + tid;
            bufC[idx] = s;
            s = fmaxf(s + bufA[idx], bufB[idx]);
        }
    }
    __syncthreads();

    // ---- phase 2: exact s trajectory (store S, 512 B/wave) + h partial hp ----
    float s[2], hp[2] = {0.0f, 0.0f};
    s[0] = bufC[tid * 2];
    s[1] = bufC[tid * 2 + 1];
    {
        const float2* pts = &PTs[sl][t0];
        float2* Sp = (float2*)(S + (size_t)t0 * NSH + (size_t)site0 * NH
                               + sl * NH + hh2 * 2);
        auto step2 = [&](float2 pt, int i) {
            const float tpos = fmaxf(pt.y, 0.0f);
            const float pnn  = (pt.y < 0.0f) ? pt.x : 0.0f;
            const float ppp  = (pt.y > 0.0f) ? pt.x : 0.0f;
            float2 sv;
            #pragma unroll
            for (int p = 0; p < 2; ++p) {
                const float m = fminf(tpos * mc[p], s[p]);
                s[p] = s[p] - m + pnn;
                const float xin = (ppp + m) * gi[p];
                hp[p] = cl[p] * (hp[p] + xin);
                (p ? sv.y : sv.x) = s[p];
            }
            Sp[(size_t)i * (NSH / 2)] = sv;        // wave: 512 B contiguous
        };
        int i = 0;
        for (; i + 4 <= len; i += 4) {
            float2 v0 = pts[i], v1 = pts[i+1], v2 = pts[i+2], v3 = pts[i+3];
            step2(v0, i); step2(v1, i+1); step2(v2, i+2); step2(v3, i+3);
        }
        for (; i < len; ++i) step2(pts[i], i);
    }
    bufA[tid * 2]     = hp[0];
    bufA[tid * 2 + 1] = hp[1];
    __syncthreads();

    // ---- resolveH: 128 threads, h0 per chunk ----
    if (tid < RES) {
        const float clr = 1.0f - sigm(w_l[tid & (NH - 1)]);
        const float pA = powf(clr, (float)LA);
        const float pB = powf(clr, (float)LB);
        float h = 0.0f;
        #pragma unroll
        for (int k = 0; k < NC; ++k) {
            const int idx = k * RES + tid;
            bufB[idx] = h;
            h = ((k < 8) ? pA : pB) * h + bufA[idx];
        }
    }
    __syncthreads();

    // ---- softmax output weights ----
    float aw[2];
    {
        float mx = -1e30f;
        #pragma unroll
        for (int j = 0; j < NH; ++j) mx = fmaxf(mx, w_o[j]);
        float den = 0.0f;
        #pragma unroll
        for (int j = 0; j < NH; ++j) den += expf(w_o[j] - mx);
        aw[0] = expf(w_o[hh2 * 2]     - mx) / den;
        aw[1] = expf(w_o[hh2 * 2 + 1] - mx) / den;
    }

    // ---- phase 3: recompute s,h; store H (512 B/wave) and Q ----
    s[0] = bufC[tid * 2];
    s[1] = bufC[tid * 2 + 1];
    float h[2];
    h[0] = bufB[tid * 2];
    h[1] = bufB[tid * 2 + 1];
    {
        const float2* pts = &PTs[sl][t0];
        float2* Hp = (float2*)(H + (size_t)t0 * NSH + (size_t)site0 * NH
                               + sl * NH + hh2 * 2);
        float* Qp = Q + (size_t)t0 * NS + site0 + sl;
        auto step3 = [&](float2 pt, int i) {
            const float tpos = fmaxf(pt.y, 0.0f);
            const float pnn  = (pt.y < 0.0f) ? pt.x : 0.0f;
            const float ppp  = (pt.y > 0.0f) ? pt.x : 0.0f;
            float2 hv;
            float qa = 0.0f;
            #pragma unroll
            for (int p = 0; p < 2; ++p) {
                const float m = fminf(tpos * mc[p], s[p]);
                s[p] = s[p] - m + pnn;
                const float xin = (ppp + m) * gi[p];
                const float q   = (xin + h[p]) * gl[p];
                h[p] = cl[p] * (h[p] + xin);
                (p ? hv.y : hv.x) = h[p];
                qa += q * aw[p];
            }
            Hp[(size_t)i * (NSH / 2)] = hv;        // wave: 512 B contiguous
            qa += __shfl_xor(qa, 1, 8);
            qa += __shfl_xor(qa, 2, 8);
            qa += __shfl_xor(qa, 4, 8);
            if (hh2 == 0) Qp[(size_t)i * NS] = qa; // wave: 32 B contiguous
        };
        int i = 0;
        for (; i + 4 <= len; i += 4) {
            float2 v0 = pts[i], v1 = pts[i+1], v2 = pts[i+2], v3 = pts[i+3];
            step3(v0, i); step3(v1, i+1); step3(v2, i+2); step3(v3, i+3);
        }
        for (; i < len; ++i) step3(pts[i], i);
    }
}

extern "C" void kernel_launch(void* const* d_in, const int* in_sizes, int n_in,
                              void* d_out, int out_size, void* d_ws, size_t ws_size,
                              hipStream_t stream) {
    const float* P   = (const float*)d_in[0];
    const float* T   = (const float*)d_in[1];
    const float* w_i = (const float*)d_in[2];
    const float* w_o = (const float*)d_in[3];
    const float* w_l = (const float*)d_in[4];
    const float* w_s = (const float*)d_in[5];

    float* Q = (float*)d_out;
    float* H = Q + (size_t)NT * NS;
    float* S = H + (size_t)NT * NS * NH;

    // No workspace needed: all intermediate state lives in LDS.
    waternet_fused<<<NS / SG, BT, 0, stream>>>(P, T, w_i, w_o, w_l, w_s, Q, H, S);
}

// Round 6
// 312.128 us; speedup vs baseline: 1.3144x; 1.0100x over previous
//
#include <hip/hip_runtime.h>

// WaterNetModel — R10: fused kernel, hh-QUAD lanes + NC=32 short chains.
//
// R9 post-mortem: store-granule theory FALSIFIED (256->512 B + occupancy
// reshape = flat). Kernel insensitive to store geometry and chain length.
// Two models fit: (A) kernel ~127 us, excess is per-iteration instruction
// cost (~2.5 instr per stored byte); (B) fixed harness cost ~250 us and
// kernel already ~65 us ~= floor (296 MB/256 CU = 46 us + prologue).
//
// R10 discriminates while being the best model-A move:
//  - thread = (chunk, site, hh-QUAD): float4 stores (half the store
//    instrs of R9), common ops amortized over 4 chains, Q-reduce = 2
//    shfl over width 4.  ~1.9 instr/B vs 2.5.
//  - NC=32 (chunks 35/34): thread chains halve, phase-1 prologue halves.
//  - keeps: 512 B full-line wave stores, in-LDS resolves, XCD swizzle,
//    unroll-4 batched ds_reads, float4 staging. LDS 119 KB, 1 block/CU.
// Pre-committed: if dur >= 308, declare harness-fixed + write-roofline.
//
// Recurrences per (site, hh):
//   snow:   s' = max(s + a, b), a = p_neg - melt_pot, b = p_neg
//           composition (A,B)∘(a,b) = (A+a, max(B+a,b))  (associative)
//   linear: h' = cl*(h + xin), cl = 1-gl -> chunk: h_out = cl^len h_in + hp

constexpr int NT  = 1096;
constexpr int NS  = 2048;
constexpr int NH  = 16;
constexpr int NSH = NS * NH;          // 32768
constexpr int SG  = 8;                // sites per block
constexpr int NC  = 32;               // chunks: 8 of len 35, 24 of len 34
constexpr int LA  = 35;
constexpr int LB  = 34;               // 8*35 + 24*34 = 1096
constexpr int BT  = 1024;             // NC(32) x SG(8) x quad(4)
constexpr int NXCD = 8;
constexpr int RES = SG * NH;          // 128 resolve lanes / states per chunk

__device__ __forceinline__ float sigm(float x) { return 1.0f / (1.0f + expf(-x)); }

__global__ __launch_bounds__(BT, 1) void waternet_fused(
    const float* __restrict__ P, const float* __restrict__ T,
    const float* __restrict__ w_i, const float* __restrict__ w_o,
    const float* __restrict__ w_l, const float* __restrict__ w_s,
    float* __restrict__ Q, float* __restrict__ H, float* __restrict__ S)
{
    __shared__ float2 PTs[SG][NT + 2];     // 70.3 KB; sl-stride -> distinct banks
    __shared__ float bufA[NC * RES];       // A / hp   (idx = tid*4+p)
    __shared__ float bufB[NC * RES];       // B / h0
    __shared__ float bufC[NC * RES];       // s0

    // XCD-chunked bijective swizzle: 256 blocks = 32 per XCD, contiguous sites.
    const int nwg  = NS / SG;                      // 256
    const int cpx  = nwg / NXCD;                   // 32
    const int bid  = (int)blockIdx.x;
    const int lbid = (bid % NXCD) * cpx + bid / NXCD;

    const int tid  = (int)threadIdx.x;
    const int q    = tid & 3;                      // hh quad: hh = 4*q + p
    const int sl   = (tid >> 2) & (SG - 1);
    const int c    = tid >> 5;                     // chunk 0..31
    const int site0 = lbid * SG;

    // chunk geometry: c<8 -> t0=35c len 35 ; c>=8 -> t0=280+34(c-8) len 34
    const int t0  = (c < 8) ? (LA * c) : (LA * 8 + LB * (c - 8));
    const int len = (c < 8) ? LA : LB;

    // ---- stage P,T for 8 sites via float4 loads ----
    for (int e = tid; e < 2 * NT; e += BT) {
        const int t  = e >> 1;
        const int hf = (e & 1) * 4;
        const float4 p4 = *(const float4*)(P + (size_t)t * NS + site0 + hf);
        const float4 t4 = *(const float4*)(T + (size_t)t * NS + site0 + hf);
        PTs[hf + 0][t] = make_float2(p4.x, t4.x);
        PTs[hf + 1][t] = make_float2(p4.y, t4.y);
        PTs[hf + 2][t] = make_float2(p4.z, t4.z);
        PTs[hf + 3][t] = make_float2(p4.w, t4.w);
    }

    float mc[4], gi[4], gl[4], cl[4];
    #pragma unroll
    for (int p = 0; p < 4; ++p) {
        const int hh = q * 4 + p;
        mc[p] = expf(w_s[hh]) + 1.0f;
        gi[p] = sigm(w_i[hh]);
        gl[p] = sigm(w_l[hh]);
        cl[p] = 1.0f - gl[p];
    }

    __syncthreads();

    // ---- phase 1: snow chunk summary (A,B), unroll x4 ----
    float A[4] = {0.0f, 0.0f, 0.0f, 0.0f};
    float B[4] = {-1e38f, -1e38f, -1e38f, -1e38f};
    {
        const float2* pts = &PTs[sl][t0];
        auto stepAB = [&](float2 pt) {
            const float tpos = fmaxf(pt.y, 0.0f);
            const float pnn  = (pt.y < 0.0f) ? pt.x : 0.0f;
            #pragma unroll
            for (int p = 0; p < 4; ++p) {
                const float at = pnn - tpos * mc[p];
                A[p] += at;
                B[p] = fmaxf(B[p] + at, pnn);
            }
        };
        int i = 0;
        for (; i + 4 <= len; i += 4) {
            float2 v0 = pts[i], v1 = pts[i+1], v2 = pts[i+2], v3 = pts[i+3];
            stepAB(v0); stepAB(v1); stepAB(v2); stepAB(v3);
        }
        for (; i < len; ++i) stepAB(pts[i]);
    }
    #pragma unroll
    for (int p = 0; p < 4; ++p) {
        bufA[tid * 4 + p] = A[p];
        bufB[tid * 4 + p] = B[p];
    }
    __syncthreads();

    // ---- resolveS: 128 threads (sl x hh), 32-step serial in LDS ----
    if (tid < RES) {
        float s = 0.0f;
        #pragma unroll
        for (int k = 0; k < NC; ++k) {
            const int idx = k * RES + tid;
            bufC[idx] = s;
            s = fmaxf(s + bufA[idx], bufB[idx]);
        }
    }
    __syncthreads();

    // ---- phase 2: exact s trajectory (store S, float4) + h partial hp ----
    float s[4], hp[4] = {0.0f, 0.0f, 0.0f, 0.0f};
    #pragma unroll
    for (int p = 0; p < 4; ++p) s[p] = bufC[tid * 4 + p];
    {
        const float2* pts = &PTs[sl][t0];
        float4* Sp = (float4*)(S + (size_t)t0 * NSH + (size_t)site0 * NH
                               + sl * NH + q * 4);
        auto step2 = [&](float2 pt, int i) {
            const float tpos = fmaxf(pt.y, 0.0f);
            const float pnn  = (pt.y < 0.0f) ? pt.x : 0.0f;
            const float ppp  = (pt.y > 0.0f) ? pt.x : 0.0f;
            float4 sv;
            #pragma unroll
            for (int p = 0; p < 4; ++p) {
                const float m = fminf(tpos * mc[p], s[p]);
                s[p] = s[p] - m + pnn;
                const float xin = (ppp + m) * gi[p];
                hp[p] = cl[p] * (hp[p] + xin);
                ((float*)&sv)[p] = s[p];
            }
            Sp[(size_t)i * (NSH / 4)] = sv;        // half-wave: 512 B contiguous
        };
        int i = 0;
        for (; i + 4 <= len; i += 4) {
            float2 v0 = pts[i], v1 = pts[i+1], v2 = pts[i+2], v3 = pts[i+3];
            step2(v0, i); step2(v1, i+1); step2(v2, i+2); step2(v3, i+3);
        }
        for (; i < len; ++i) step2(pts[i], i);
    }
    #pragma unroll
    for (int p = 0; p < 4; ++p) bufA[tid * 4 + p] = hp[p];
    __syncthreads();

    // ---- resolveH: 128 threads, h0 per chunk ----
    if (tid < RES) {
        const float clr = 1.0f - sigm(w_l[tid & (NH - 1)]);
        const float pA = powf(clr, (float)LA);
        const float pB = powf(clr, (float)LB);
        float h = 0.0f;
        #pragma unroll
        for (int k = 0; k < NC; ++k) {
            const int idx = k * RES + tid;
            bufB[idx] = h;
            h = ((k < 8) ? pA : pB) * h + bufA[idx];
        }
    }
    __syncthreads();

    // ---- softmax output weights ----
    float aw[4];
    {
        float mx = -1e30f;
        #pragma unroll
        for (int j = 0; j < NH; ++j) mx = fmaxf(mx, w_o[j]);
        float den = 0.0f;
        #pragma unroll
        for (int j = 0; j < NH; ++j) den += expf(w_o[j] - mx);
        #pragma unroll
        for (int p = 0; p < 4; ++p) aw[p] = expf(w_o[q * 4 + p] - mx) / den;
    }

    // ---- phase 3: recompute s,h; store H (float4) and Q (2-shfl reduce) ----
    float h[4];
    #pragma unroll
    for (int p = 0; p < 4; ++p) {
        s[p] = bufC[tid * 4 + p];
        h[p] = bufB[tid * 4 + p];
    }
    {
        const float2* pts = &PTs[sl][t0];
        float4* Hp = (float4*)(H + (size_t)t0 * NSH + (size_t)site0 * NH
                               + sl * NH + q * 4);
        float* Qp = Q + (size_t)t0 * NS + site0 + sl;
        auto step3 = [&](float2 pt, int i) {
            const float tpos = fmaxf(pt.y, 0.0f);
            const float pnn  = (pt.y < 0.0f) ? pt.x : 0.0f;
            const float ppp  = (pt.y > 0.0f) ? pt.x : 0.0f;
            float4 hv;
            float qa = 0.0f;
            #pragma unroll
            for (int p = 0; p < 4; ++p) {
                const float m = fminf(tpos * mc[p], s[p]);
                s[p] = s[p] - m + pnn;
                const float xin = (ppp + m) * gi[p];
                const float qq  = (xin + h[p]) * gl[p];
                h[p] = cl[p] * (h[p] + xin);
                ((float*)&hv)[p] = h[p];
                qa += qq * aw[p];
            }
            Hp[(size_t)i * (NSH / 4)] = hv;        // half-wave: 512 B contiguous
            qa += __shfl_xor(qa, 1, 4);
            qa += __shfl_xor(qa, 2, 4);
            if (q == 0) Qp[(size_t)i * NS] = qa;   // 8 lanes: 32 B contiguous
        };
        int i = 0;
        for (; i + 4 <= len; i += 4) {
            float2 v0 = pts[i], v1 = pts[i+1], v2 = pts[i+2], v3 = pts[i+3];
            step3(v0, i); step3(v1, i+1); step3(v2, i+2); step3(v3, i+3);
        }
        for (; i < len; ++i) step3(pts[i], i);
    }
}

extern "C" void kernel_launch(void* const* d_in, const int* in_sizes, int n_in,
                              void* d_out, int out_size, void* d_ws, size_t ws_size,
                              hipStream_t stream) {
    const float* P   = (const float*)d_in[0];
    const float* T   = (const float*)d_in[1];
    const float* w_i = (const float*)d_in[2];
    const float* w_o = (const float*)d_in[3];
    const float* w_l = (const float*)d_in[4];
    const float* w_s = (const float*)d_in[5];

    float* Q = (float*)d_out;
    float* H = Q + (size_t)NT * NS;
    float* S = H + (size_t)NT * NS * NH;

    // No workspace needed: all intermediate state lives in LDS.
    waternet_fused<<<NS / SG, BT, 0, stream>>>(P, T, w_i, w_o, w_l, w_s, Q, H, S);
}